// Round 5
// baseline (1301.430 us; speedup 1.0000x reference)
//
#include <hip/hip_runtime.h>
#include <hip/hip_bf16.h>
#include <stdint.h>

#define DEVI static __device__ __forceinline__

// Problem constants
constexpr int NPTS = 4096;     // N
constexpr int BN   = 16384;    // B*N

// ---------------- ws layout (float offsets) ----------------
constexpr size_t OFF_FLAG = 0;                          // unsigned flag (1=fp32 inputs)
constexpr size_t OFF_XYZS = 16;                         // float4[BN]  (x,y,z,sq)
constexpr size_t OFF_WPK  = OFF_XYZS + 65536;           // float[256*144] att-MLP pack
constexpr size_t OFF_WPOS = OFF_WPK + 256 * 144;        // float[64*80] pos-MLP pack
constexpr size_t OFF_B2   = OFF_WPOS + 64 * 80;         // float[64] b_att2
constexpr size_t OFF_BP2  = OFF_B2 + 64;                // float[64] b_pos2
constexpr size_t OFF_WQKV = OFF_BP2 + 64;               // float[192*64]
constexpr size_t OFF_IDX  = OFF_WQKV + 192 * 64;        // uint[BN*16]
constexpr size_t OFF_KT   = OFF_IDX + (size_t)BN * 16;  // float[BN*64] (fast path only)
constexpr size_t OFF_VT   = OFF_KT + (size_t)BN * 64;   // float[BN*64] (fast path only)
constexpr size_t FULL_FLOATS = OFF_VT + (size_t)BN * 64;   // ~9.92 MB

DEVI float b2f(__hip_bfloat16 h) { return __bfloat162float(h); }

DEVI float us2f(unsigned short u) {
    __hip_bfloat16 h;
    *(unsigned short*)&h = u;
    return __bfloat162float(h);
}

DEVI unsigned short f2us(float f) {
    __hip_bfloat16 h = __float2bfloat16(f);
    return *(unsigned short*)&h;
}

DEVI float ldin(const void* p, size_t i, int f32) {
    return f32 ? ((const float*)p)[i] : b2f(((const __hip_bfloat16*)p)[i]);
}

DEVI unsigned long long shflx64(unsigned long long v, int m) {
    unsigned lo = __shfl_xor((unsigned)(v & 0xffffffffull), m, 64);
    unsigned hi = __shfl_xor((unsigned)(v >> 32), m, 64);
    return ((unsigned long long)hi << 32) | lo;
}

// ---------------- dtype detector ----------------
__global__ void detect_kernel(const void* xyz, unsigned* flagp) {
    __shared__ int s;
    int t = threadIdx.x;
    if (t == 0) s = 0;
    __syncthreads();
    const unsigned short* u = (const unsigned short*)xyz;
    int cnt = 0;
    for (int i = t; i < 2048; i += 256) {
        unsigned e = (u[i] >> 7) & 0xFFu;
        cnt += (e >= 140u);
    }
    atomicAdd(&s, cnt);
    __syncthreads();
    if (t == 0) *flagp = (s > 16) ? 1u : 0u;
}

// ---------------- prep: xyzs(float4) + packed fp32 weights ----------------
__global__ void prep_kernel(const void* xyz, const void* w_qkv,
                            const void* w_pos1, const void* b_pos1,
                            const void* w_pos2, const void* b_pos2,
                            const void* w_att1, const void* b_att1,
                            const void* w_att2, const void* b_att2,
                            float* ws) {
    int f32 = (int)((const unsigned*)ws)[OFF_FLAG];
    int t = threadIdx.x;
    int blk = blockIdx.x;
    if (blk == 0) {
        float* wp = ws + OFF_WPK + (size_t)t * 144;
        for (int d = 0; d < 64; d++) wp[d]      = ldin(w_att1, t * 64 + d, f32);
        for (int d = 0; d < 64; d++) wp[64 + d] = ldin(w_att2, d * 256 + t, f32);
        wp[128] = ldin(b_att1, t, f32);
    } else if (blk == 1) {
        if (t < 64) {
            float* wp = ws + OFF_WPOS + (size_t)t * 80;
            wp[0] = ldin(w_pos1, t * 3 + 0, f32);
            wp[1] = ldin(w_pos1, t * 3 + 1, f32);
            wp[2] = ldin(w_pos1, t * 3 + 2, f32);
            wp[3] = ldin(b_pos1, t, f32);
            for (int d = 0; d < 64; d++) wp[4 + d] = ldin(w_pos2, d * 64 + t, f32);
            ws[OFF_B2 + t]  = ldin(b_att2, t, f32);
            ws[OFF_BP2 + t] = ldin(b_pos2, t, f32);
        }
        for (int i = t; i < 192 * 64; i += 256) ws[OFF_WQKV + i] = ldin(w_qkv, i, f32);
    } else {
        int gid = (blk - 2) * 256 + t;   // 0..16383
        int b = gid >> 12, n = gid & 4095;
        float x = ldin(xyz, (size_t)(b * 3 + 0) * NPTS + n, f32);
        float y = ldin(xyz, (size_t)(b * 3 + 1) * NPTS + n, f32);
        float z = ldin(xyz, (size_t)(b * 3 + 2) * NPTS + n, f32);
        float sq = __fadd_rn(__fadd_rn(__fmul_rn(x, x), __fmul_rn(y, y)), __fmul_rn(z, z));
        ((float4*)(ws + OFF_XYZS))[gid] = make_float4(x, y, z, sq);
    }
}

// ---------------- kv GEMM (fast path): kt/vt row-major [n][d], fp32 ----------------
__global__ void kv_kernel(const void* points, float* ws) {
    __shared__ float T[128 * 65];
    int f32 = (int)((const unsigned*)ws)[OFF_FLAG];
    const float* wq = ws + OFF_WQKV + 64 * 64;  // rows 64..191 (k then v)
    int t = threadIdx.x;
    int wid = __builtin_amdgcn_readfirstlane(t >> 6);
    int lane = t & 63;
    int b = blockIdx.x >> 6;
    int n0 = (blockIdx.x & 63) * 64;

    float P[64];
#pragma unroll
    for (int d = 0; d < 64; d++)
        P[d] = ldin(points, (size_t)(b * 64 + d) * NPTS + n0 + lane, f32);

    for (int i = 0; i < 32; i++) {
        int o = wid + 4 * i;
        const float* wr = wq + o * 64;
        float acc = 0.f;
#pragma unroll
        for (int d = 0; d < 64; d++) acc = fmaf(wr[d], P[d], acc);
        T[o * 65 + lane] = acc;
    }
    __syncthreads();

#pragma unroll
    for (int a2 = 0; a2 < 2; a2++) {
        float* dst = ws + (a2 == 0 ? OFF_KT : OFF_VT);
#pragma unroll
        for (int j = 0; j < 4; j++) {
            int ci = j * 256 + t;
            int np = ci >> 4, dp = ci & 15;
            float4 v;
            v.x = T[(a2 * 64 + dp * 4 + 0) * 65 + np];
            v.y = T[(a2 * 64 + dp * 4 + 1) * 65 + np];
            v.z = T[(a2 * 64 + dp * 4 + 2) * 65 + np];
            v.w = T[(a2 * 64 + dp * 4 + 3) * 65 + np];
            *(float4*)(dst + ((size_t)((b << 12) + n0 + np)) * 64 + dp * 4) = v;
        }
    }
}

// ---------------- KNN: wave-per-row, exact top-16 ----------------
template <int NK>
DEVI unsigned long long knn_row(const float4* base, float4 pn, int lane,
                                unsigned* out_row, unsigned long long* kept_worst) {
    unsigned long long arr[NK];
#pragma unroll
    for (int i = 0; i < NK; i++) arr[i] = ~0ull;
    float sqn = pn.w;
#pragma unroll 4
    for (int j = 0; j < 64; j++) {
        int m = (j << 6) + lane;
        float4 pm = base[m];
        float dot = __fadd_rn(__fadd_rn(__fmul_rn(pn.x, pm.x), __fmul_rn(pn.y, pm.y)),
                              __fmul_rn(pn.z, pm.z));
        float d2 = __fsub_rn(__fadd_rn(sqn, pm.w), __fmul_rn(2.0f, dot));
        unsigned ub = __float_as_uint(d2);
        ub = (ub >> 31) ? ~ub : (ub | 0x80000000u);
        unsigned long long key = ((unsigned long long)ub << 32) | (unsigned)m;
#pragma unroll
        for (int i = 0; i < NK; i++) {
            bool lt = key < arr[i];
            unsigned long long lo = lt ? key : arr[i];
            key = lt ? arr[i] : key;
            arr[i] = lo;
        }
    }
    unsigned long long kw = arr[NK - 1];
    unsigned long long v16 = 0;
    for (int r = 0; r < 16; r++) {
        unsigned long long mn = arr[0];
#pragma unroll
        for (int s = 1; s < 64; s <<= 1) {
            unsigned long long o = shflx64(mn, s);
            if (o < mn) mn = o;
        }
        if (arr[0] == mn) {
#pragma unroll
            for (int i = 0; i < NK - 1; i++) arr[i] = arr[i + 1];
            arr[NK - 1] = ~0ull;
            out_row[r] = (unsigned)(mn & 0xffffffffu);
        }
        v16 = mn;
    }
    *kept_worst = kw;
    return v16;
}

__global__ void knn_kernel(float* ws) {
    int t = threadIdx.x;
    int wid = t >> 6, lane = t & 63;
    int row = blockIdx.x * 4 + wid;
    int b = row >> 12;
    const float4* base = (const float4*)(ws + OFF_XYZS) + ((size_t)b << 12);
    float4 pn = base[row & 4095];
    unsigned* orow = (unsigned*)(ws + OFF_IDX) + (size_t)row * 16;

    unsigned long long kw;
    unsigned long long v16 = knn_row<6>(base, pn, lane, orow, &kw);
    if (__any(kw < v16)) {
        knn_row<16>(base, pn, lane, orow, &kw);
    }
}

// ---------------- fused main v2 (USE_KV): 2 lanes per (n,k) column ----------------
// lane = k(4b) + 16*nh(1b) + 32*half(1b). Wave: 2 n's x 16 k x 2 halves.
// Block: 4 waves = 8 n's. Per-lane state: rpe[32]+X[32]+sim[32] -> no spill.
__global__ __launch_bounds__(256, 4) void pt_main2(const float* __restrict__ ws,
                                                   const void* __restrict__ points,
                                                   void* __restrict__ out) {
    __shared__ float PL[64 * 8];    // [d][nl]
    __shared__ float QL[8 * 68];    // [nl][o] stride 68
    __shared__ float OUTS[64 * 8];  // [d][nl]

    int f32 = (int)((const unsigned*)ws)[OFF_FLAG];
    const float* wpack = ws + OFF_WPK;
    const float* wpos  = ws + OFF_WPOS;
    const float* b2p   = ws + OFF_B2;
    const float* bp2p  = ws + OFF_BP2;
    const float* wq    = ws + OFF_WQKV;
    const unsigned* idxws = (const unsigned*)(ws + OFF_IDX);
    const float4* xyzs = (const float4*)(ws + OFF_XYZS);

    int t = threadIdx.x;
    int wid = t >> 6, lane = t & 63;

    // XCD swizzle: XCD x = bx&7 handles batch b = x&3 (KT+VT for one b = 4 MB = one L2)
    int bx = blockIdx.x;               // grid 2048
    int x = bx & 7, j = bx >> 3;       // j in 0..255
    int b = x & 3;
    int n0 = (((x >> 2) << 8) + j) << 3;   // ((x>>2)*256 + j) * 8

    // ---- phase 0a: stage 8 point-columns into LDS
    {
        int d = t >> 2, c = t & 3;
        size_t base = (size_t)(b * 64 + d) * NPTS + n0 + c * 2;
        if (f32) {
            float2 pv = *(const float2*)((const float*)points + base);
            PL[d * 8 + c * 2 + 0] = pv.x;
            PL[d * 8 + c * 2 + 1] = pv.y;
        } else {
            ushort2 pv = *(const ushort2*)((const unsigned short*)points + base);
            PL[d * 8 + c * 2 + 0] = us2f(pv.x);
            PL[d * 8 + c * 2 + 1] = us2f(pv.y);
        }
    }
    __syncthreads();

    // ---- phase 0b: q[nl][o] (8 n x 64 o), lane = nl(3b) + 8*sg(3b)
    {
        int nl = lane & 7, sg = lane >> 3;
        for (int oi = 0; oi < 16; oi++) {
            int o = wid * 16 + oi;
            const float* wr = wq + o * 64 + sg * 8;
            float p = 0.f;
#pragma unroll
            for (int jj = 0; jj < 8; jj++) p = fmaf(wr[jj], PL[(sg * 8 + jj) * 8 + nl], p);
            p += __shfl_xor(p, 8, 64);
            p += __shfl_xor(p, 16, 64);
            p += __shfl_xor(p, 32, 64);
            if (lane < 8) QL[nl * 68 + o] = p;
        }
    }
    __syncthreads();

    // ---- per-lane task: (n, k, half)
    int k = lane & 15, nh = (lane >> 4) & 1, half = lane >> 5;
    int nl = wid * 2 + nh;
    int n = n0 + nl;
    int row = (b << 12) + n;
    int d0 = half * 32;
    unsigned m = idxws[(size_t)row * 16 + k] & 4095u;
    int mrow = (b << 12) + (int)m;

    float4 pn = xyzs[row];
    float4 pmx = xyzs[mrow];
    float rx = pn.x - pmx.x, ry = pn.y - pmx.y, rz = pn.z - pmx.z;

    // ---- pos MLP -> rpe (this lane's 32 d's)
    float rpe[32];
#pragma unroll
    for (int i = 0; i < 32; i++) rpe[i] = bp2p[d0 + i];
#pragma unroll 2
    for (int o = 0; o < 64; o++) {
        const float* wr = wpos + o * 80;
        float hp = fmaf(wr[0], rx, fmaf(wr[1], ry, fmaf(wr[2], rz, wr[3])));
        hp = fmaxf(hp, 0.f);
        const float* w2 = wr + 4 + d0;
#pragma unroll
        for (int i = 0; i < 32; i++) rpe[i] = fmaf(w2[i], hp, rpe[i]);
    }

    // ---- X = (q - k) + rpe
    float X[32];
    {
        const float4* q4 = (const float4*)(QL + nl * 68 + d0);
        const float4* kr = (const float4*)(ws + OFF_KT + (size_t)mrow * 64 + d0);
#pragma unroll
        for (int d4 = 0; d4 < 8; d4++) {
            float4 qv = q4[d4];
            float4 kv = kr[d4];
            X[4 * d4 + 0] = (qv.x - kv.x) + rpe[4 * d4 + 0];
            X[4 * d4 + 1] = (qv.y - kv.y) + rpe[4 * d4 + 1];
            X[4 * d4 + 2] = (qv.z - kv.z) + rpe[4 * d4 + 2];
            X[4 * d4 + 3] = (qv.w - kv.w) + rpe[4 * d4 + 3];
        }
    }

    // ---- att MLP: h via cross-half shuffle; sim over this lane's 32 d's
    float sim[32];
#pragma unroll
    for (int i = 0; i < 32; i++) sim[i] = b2p[d0 + i];
#pragma unroll 2
    for (int o = 0; o < 256; o++) {
        const float* wr = wpack + (size_t)o * 144;
        const float* w1 = wr + d0;
        float h0 = 0.f, h1 = 0.f;
#pragma unroll
        for (int jj = 0; jj < 16; jj++) {
            h0 = fmaf(w1[jj],      X[jj],      h0);
            h1 = fmaf(w1[16 + jj], X[16 + jj], h1);
        }
        float hp = h0 + h1;
        float h = hp + __shfl_xor(hp, 32, 64) + wr[128];
        h = fmaxf(h, 0.f);
        const float* w2 = wr + 64 + d0;
#pragma unroll
        for (int i = 0; i < 32; i++) sim[i] = fmaf(w2[i], h, sim[i]);
    }

    // ---- softmax over k (16-lane groups; nh,half fixed under masks 1,2,4,8) + agg
    {
        const float4* vr = (const float4*)(ws + OFF_VT + (size_t)mrow * 64 + d0);
#pragma unroll
        for (int d4 = 0; d4 < 8; d4++) {
            float4 vv = vr[d4];
            float w4[4] = {vv.x + rpe[4 * d4 + 0], vv.y + rpe[4 * d4 + 1],
                           vv.z + rpe[4 * d4 + 2], vv.w + rpe[4 * d4 + 3]};
#pragma unroll
            for (int jj = 0; jj < 4; jj++) {
                int i = 4 * d4 + jj;
                float s = sim[i];
                float mx = s;
                mx = fmaxf(mx, __shfl_xor(mx, 1, 64));
                mx = fmaxf(mx, __shfl_xor(mx, 2, 64));
                mx = fmaxf(mx, __shfl_xor(mx, 4, 64));
                mx = fmaxf(mx, __shfl_xor(mx, 8, 64));
                float e = __expf(s - mx);
                float sm = e;
                sm += __shfl_xor(sm, 1, 64);
                sm += __shfl_xor(sm, 2, 64);
                sm += __shfl_xor(sm, 4, 64);
                sm += __shfl_xor(sm, 8, 64);
                float p = e * w4[jj];
                p += __shfl_xor(p, 1, 64);
                p += __shfl_xor(p, 2, 64);
                p += __shfl_xor(p, 4, 64);
                p += __shfl_xor(p, 8, 64);
                if (k == 0) OUTS[(d0 + i) * 8 + nl] = p / sm;
            }
        }
    }
    __syncthreads();

    // ---- coalesced store (dtype-dispatched)
    {
        int d = t >> 2, c = t & 3;
        float2 v = *(const float2*)&OUTS[d * 8 + c * 2];
        size_t ofs = (size_t)(b * 64 + d) * NPTS + n0 + c * 2;
        if (f32) {
            *(float2*)((float*)out + ofs) = v;
        } else {
            unsigned pk = (unsigned)f2us(v.x) | ((unsigned)f2us(v.y) << 16);
            *(unsigned*)((unsigned short*)out + ofs) = pk;
        }
    }
}

// ---------------- fused main (compact fallback, !USE_KV): round-4 version ----------------
__global__ __launch_bounds__(256, 2) void pt_main_compact(const float* __restrict__ ws,
                                                          const void* __restrict__ points,
                                                          void* __restrict__ out) {
    __shared__ float PL[64 * 16];
    __shared__ float QL[16 * 68];
    __shared__ float OUTS[64 * 16];

    int f32 = (int)((const unsigned*)ws)[OFF_FLAG];
    const float* wpack = ws + OFF_WPK;
    const float* wpos  = ws + OFF_WPOS;
    const float* b2p   = ws + OFF_B2;
    const float* bp2p  = ws + OFF_BP2;
    const float* wq    = ws + OFF_WQKV;
    const unsigned* idxws = (const unsigned*)(ws + OFF_IDX);
    const float4* xyzs = (const float4*)(ws + OFF_XYZS);

    int t = threadIdx.x;
    int wid = t >> 6, lane = t & 63;

    int bx = blockIdx.x;
    int x = bx & 7, j = bx >> 3;
    int b = x & 3;
    int n0 = ((((x >> 2) << 7) + j) << 4);

    {
        int d = t >> 2, c4 = t & 3;
        size_t base = (size_t)(b * 64 + d) * NPTS + n0 + c4 * 4;
        if (f32) {
            float4 pv = *(const float4*)((const float*)points + base);
            PL[d * 16 + c4 * 4 + 0] = pv.x;
            PL[d * 16 + c4 * 4 + 1] = pv.y;
            PL[d * 16 + c4 * 4 + 2] = pv.z;
            PL[d * 16 + c4 * 4 + 3] = pv.w;
        } else {
            ushort4 pv = *(const ushort4*)((const unsigned short*)points + base);
            PL[d * 16 + c4 * 4 + 0] = us2f(pv.x);
            PL[d * 16 + c4 * 4 + 1] = us2f(pv.y);
            PL[d * 16 + c4 * 4 + 2] = us2f(pv.z);
            PL[d * 16 + c4 * 4 + 3] = us2f(pv.w);
        }
    }
    __syncthreads();

    {
        int sg = lane >> 4, nl = lane & 15;
        for (int oi = 0; oi < 16; oi++) {
            int o = wid * 16 + oi;
            const float* wr = wq + o * 64 + sg * 16;
            float p = 0.f;
#pragma unroll
            for (int jj = 0; jj < 16; jj++) p = fmaf(wr[jj], PL[(sg * 16 + jj) * 16 + nl], p);
            p += __shfl_xor(p, 16, 64);
            p += __shfl_xor(p, 32, 64);
            if (lane < 16) QL[nl * 68 + o] = p;
        }
    }
    __syncthreads();

    int k = lane & 15, nsub = lane >> 4;
    int nl = wid * 4 + nsub;
    int n = n0 + nl;
    int row = (b << 12) + n;
    unsigned m = idxws[(size_t)row * 16 + k] & 4095u;

    float4 pn = xyzs[row];
    float4 pmx = xyzs[(b << 12) + (int)m];
    float rx = pn.x - pmx.x, ry = pn.y - pmx.y, rz = pn.z - pmx.z;

    float R[64];
#pragma unroll
    for (int d = 0; d < 64; d++) R[d] = bp2p[d];
#pragma unroll 2
    for (int o = 0; o < 64; o++) {
        const float* wr = wpos + o * 80;
        float hp = fmaf(wr[0], rx, fmaf(wr[1], ry, fmaf(wr[2], rz, wr[3])));
        hp = fmaxf(hp, 0.f);
#pragma unroll
        for (int d = 0; d < 64; d++) R[d] = fmaf(wr[4 + d], hp, R[d]);
    }

    float Pm[64];
#pragma unroll
    for (int d = 0; d < 64; d++)
        Pm[d] = ldin(points, ((size_t)(b * 64 + d) << 12) + (int)m, f32);
    {
        const float* qrow = QL + nl * 68;
#pragma unroll 2
        for (int d = 0; d < 64; d++) {
            const float* wr = wq + (64 + d) * 64;
            float kd = 0.f;
#pragma unroll
            for (int dd = 0; dd < 64; dd++) kd = fmaf(wr[dd], Pm[dd], kd);
            R[d] = (qrow[d] - kd) + R[d];
        }
    }

    float sim[64];
#pragma unroll
    for (int d = 0; d < 64; d++) sim[d] = b2p[d];
#pragma unroll 2
    for (int o = 0; o < 256; o++) {
        const float* wr = wpack + (size_t)o * 144;
        float h0 = 0.f, h1 = 0.f, h2 = 0.f, h3 = 0.f;
#pragma unroll
        for (int jj = 0; jj < 16; jj++) {
            h0 = fmaf(wr[jj],      R[jj],      h0);
            h1 = fmaf(wr[16 + jj], R[16 + jj], h1);
            h2 = fmaf(wr[32 + jj], R[32 + jj], h2);
            h3 = fmaf(wr[48 + jj], R[48 + jj], h3);
        }
        float h = ((h0 + h1) + (h2 + h3)) + wr[128];
        h = fmaxf(h, 0.f);
#pragma unroll
        for (int d = 0; d < 64; d++) sim[d] = fmaf(wr[64 + d], h, sim[d]);
    }

    {
        const float4* q4 = (const float4*)(QL + nl * 68);
#pragma unroll
        for (int d4 = 0; d4 < 16; d4++) {
            float vvv[4], rpe4[4];
            float4 qv = q4[d4];
#pragma unroll
            for (int jj = 0; jj < 4; jj++) {
                int d = 4 * d4 + jj;
                const float* wrk = wq + (64 + d) * 64;
                const float* wrv = wq + (128 + d) * 64;
                float kd = 0.f, vd = 0.f;
#pragma unroll
                for (int dd = 0; dd < 64; dd++) {
                    kd = fmaf(wrk[dd], Pm[dd], kd);
                    vd = fmaf(wrv[dd], Pm[dd], vd);
                }
                float qj = (jj == 0) ? qv.x : (jj == 1) ? qv.y : (jj == 2) ? qv.z : qv.w;
                rpe4[jj] = R[d] - (qj - kd);
                vvv[jj] = vd;
            }
#pragma unroll
            for (int jj = 0; jj < 4; jj++) {
                int d = 4 * d4 + jj;
                float s = sim[d];
                float mx = s;
                mx = fmaxf(mx, __shfl_xor(mx, 1, 64));
                mx = fmaxf(mx, __shfl_xor(mx, 2, 64));
                mx = fmaxf(mx, __shfl_xor(mx, 4, 64));
                mx = fmaxf(mx, __shfl_xor(mx, 8, 64));
                float e = __expf(s - mx);
                float sm = e;
                sm += __shfl_xor(sm, 1, 64);
                sm += __shfl_xor(sm, 2, 64);
                sm += __shfl_xor(sm, 4, 64);
                sm += __shfl_xor(sm, 8, 64);
                float v2 = vvv[jj] + rpe4[jj];
                float p = e * v2;
                p += __shfl_xor(p, 1, 64);
                p += __shfl_xor(p, 2, 64);
                p += __shfl_xor(p, 4, 64);
                p += __shfl_xor(p, 8, 64);
                if (k == 0) OUTS[d * 16 + nl] = p / sm;
            }
        }
    }
    __syncthreads();

    {
        int d = t >> 2, c = t & 3;
        float4 v = *(const float4*)&OUTS[d * 16 + c * 4];
        size_t ofs = (size_t)(b * 64 + d) * NPTS + n0 + c * 4;
        if (f32) {
            *(float4*)((float*)out + ofs) = v;
        } else {
            uint2 pk;
            pk.x = (unsigned)f2us(v.x) | ((unsigned)f2us(v.y) << 16);
            pk.y = (unsigned)f2us(v.z) | ((unsigned)f2us(v.w) << 16);
            *(uint2*)((unsigned short*)out + ofs) = pk;
        }
    }
}

// ---------------- host ----------------
extern "C" void kernel_launch(void* const* d_in, const int* in_sizes, int n_in,
                              void* d_out, int out_size, void* d_ws, size_t ws_size,
                              hipStream_t stream) {
    const void* xyz    = d_in[0];
    const void* points = d_in[1];
    const void* w_qkv  = d_in[2];
    const void* w_pos1 = d_in[3];
    const void* b_pos1 = d_in[4];
    const void* w_pos2 = d_in[5];
    const void* b_pos2 = d_in[6];
    const void* w_att1 = d_in[7];
    const void* b_att1 = d_in[8];
    const void* w_att2 = d_in[9];
    const void* b_att2 = d_in[10];
    float* ws = (float*)d_ws;

    bool use_kv = ws_size >= FULL_FLOATS * sizeof(float);

    hipLaunchKernelGGL(detect_kernel, dim3(1), dim3(256), 0, stream,
                       xyz, (unsigned*)ws + OFF_FLAG);
    hipLaunchKernelGGL(prep_kernel, dim3(66), dim3(256), 0, stream,
                       xyz, w_qkv, w_pos1, b_pos1, w_pos2, b_pos2,
                       w_att1, b_att1, w_att2, b_att2, ws);
    if (use_kv)
        hipLaunchKernelGGL(kv_kernel, dim3(256), dim3(256), 0, stream, points, ws);
    hipLaunchKernelGGL(knn_kernel, dim3(4096), dim3(256), 0, stream, ws);
    if (use_kv)
        hipLaunchKernelGGL(pt_main2, dim3(2048), dim3(256), 0, stream, (const float*)ws, points, d_out);
    else
        hipLaunchKernelGGL(pt_main_compact, dim3(1024), dim3(256), 0, stream, (const float*)ws, points, d_out);
}

// Round 6
// 987.083 us; speedup vs baseline: 1.3185x; 1.3185x over previous
//
#include <hip/hip_runtime.h>
#include <hip/hip_bf16.h>
#include <stdint.h>

#define DEVI static __device__ __forceinline__

// Problem constants
constexpr int NPTS = 4096;     // N
constexpr int BN   = 16384;    // B*N

// ---------------- ws layout (float offsets) ----------------
constexpr size_t OFF_FLAG = 0;                          // unsigned flag (1=fp32 inputs)
constexpr size_t OFF_XYZS = 16;                         // float4[BN]  (x,y,z,sq)
constexpr size_t OFF_WPK  = OFF_XYZS + 65536;           // float[256*144] att-MLP pack
constexpr size_t OFF_WPOS = OFF_WPK + 256 * 144;        // float[64*80] pos-MLP pack
constexpr size_t OFF_B2   = OFF_WPOS + 64 * 80;         // float[64] b_att2
constexpr size_t OFF_BP2  = OFF_B2 + 64;                // float[64] b_pos2
constexpr size_t OFF_WQKV = OFF_BP2 + 64;               // float[192*64]
constexpr size_t OFF_IDX  = OFF_WQKV + 192 * 64;        // uint[BN*16]
constexpr size_t OFF_KT   = OFF_IDX + (size_t)BN * 16;  // float[BN*64] (fast path only)
constexpr size_t OFF_VT   = OFF_KT + (size_t)BN * 64;   // float[BN*64] (fast path only)
constexpr size_t FULL_FLOATS = OFF_VT + (size_t)BN * 64;   // ~9.92 MB

DEVI float b2f(__hip_bfloat16 h) { return __bfloat162float(h); }

DEVI float us2f(unsigned short u) {
    __hip_bfloat16 h;
    *(unsigned short*)&h = u;
    return __bfloat162float(h);
}

DEVI unsigned short f2us(float f) {
    __hip_bfloat16 h = __float2bfloat16(f);
    return *(unsigned short*)&h;
}

DEVI float ldin(const void* p, size_t i, int f32) {
    return f32 ? ((const float*)p)[i] : b2f(((const __hip_bfloat16*)p)[i]);
}

DEVI unsigned long long shflx64(unsigned long long v, int m) {
    unsigned lo = __shfl_xor((unsigned)(v & 0xffffffffull), m, 64);
    unsigned hi = __shfl_xor((unsigned)(v >> 32), m, 64);
    return ((unsigned long long)hi << 32) | lo;
}

// ---------------- dtype detector ----------------
__global__ void detect_kernel(const void* xyz, unsigned* flagp) {
    __shared__ int s;
    int t = threadIdx.x;
    if (t == 0) s = 0;
    __syncthreads();
    const unsigned short* u = (const unsigned short*)xyz;
    int cnt = 0;
    for (int i = t; i < 2048; i += 256) {
        unsigned e = (u[i] >> 7) & 0xFFu;
        cnt += (e >= 140u);
    }
    atomicAdd(&s, cnt);
    __syncthreads();
    if (t == 0) *flagp = (s > 16) ? 1u : 0u;
}

// ---------------- prep: xyzs(float4) + packed fp32 weights ----------------
__global__ void prep_kernel(const void* xyz, const void* w_qkv,
                            const void* w_pos1, const void* b_pos1,
                            const void* w_pos2, const void* b_pos2,
                            const void* w_att1, const void* b_att1,
                            const void* w_att2, const void* b_att2,
                            float* ws) {
    int f32 = (int)((const unsigned*)ws)[OFF_FLAG];
    int t = threadIdx.x;
    int blk = blockIdx.x;
    if (blk == 0) {
        float* wp = ws + OFF_WPK + (size_t)t * 144;
        for (int d = 0; d < 64; d++) wp[d]      = ldin(w_att1, t * 64 + d, f32);
        for (int d = 0; d < 64; d++) wp[64 + d] = ldin(w_att2, d * 256 + t, f32);
        wp[128] = ldin(b_att1, t, f32);
    } else if (blk == 1) {
        if (t < 64) {
            float* wp = ws + OFF_WPOS + (size_t)t * 80;
            wp[0] = ldin(w_pos1, t * 3 + 0, f32);
            wp[1] = ldin(w_pos1, t * 3 + 1, f32);
            wp[2] = ldin(w_pos1, t * 3 + 2, f32);
            wp[3] = ldin(b_pos1, t, f32);
            for (int d = 0; d < 64; d++) wp[4 + d] = ldin(w_pos2, d * 64 + t, f32);
            ws[OFF_B2 + t]  = ldin(b_att2, t, f32);
            ws[OFF_BP2 + t] = ldin(b_pos2, t, f32);
        }
        for (int i = t; i < 192 * 64; i += 256) ws[OFF_WQKV + i] = ldin(w_qkv, i, f32);
    } else {
        int gid = (blk - 2) * 256 + t;   // 0..16383
        int b = gid >> 12, n = gid & 4095;
        float x = ldin(xyz, (size_t)(b * 3 + 0) * NPTS + n, f32);
        float y = ldin(xyz, (size_t)(b * 3 + 1) * NPTS + n, f32);
        float z = ldin(xyz, (size_t)(b * 3 + 2) * NPTS + n, f32);
        float sq = __fadd_rn(__fadd_rn(__fmul_rn(x, x), __fmul_rn(y, y)), __fmul_rn(z, z));
        ((float4*)(ws + OFF_XYZS))[gid] = make_float4(x, y, z, sq);
    }
}

// ---------------- kv GEMM (fast path): kt/vt row-major [n][d], fp32 ----------------
__global__ void kv_kernel(const void* points, float* ws) {
    __shared__ float T[128 * 65];
    int f32 = (int)((const unsigned*)ws)[OFF_FLAG];
    const float* wq = ws + OFF_WQKV + 64 * 64;  // rows 64..191 (k then v)
    int t = threadIdx.x;
    int wid = __builtin_amdgcn_readfirstlane(t >> 6);
    int lane = t & 63;
    int b = blockIdx.x >> 6;
    int n0 = (blockIdx.x & 63) * 64;

    float P[64];
#pragma unroll
    for (int d = 0; d < 64; d++)
        P[d] = ldin(points, (size_t)(b * 64 + d) * NPTS + n0 + lane, f32);

    for (int i = 0; i < 32; i++) {
        int o = wid + 4 * i;
        const float* wr = wq + o * 64;
        float acc = 0.f;
#pragma unroll
        for (int d = 0; d < 64; d++) acc = fmaf(wr[d], P[d], acc);
        T[o * 65 + lane] = acc;
    }
    __syncthreads();

#pragma unroll
    for (int a2 = 0; a2 < 2; a2++) {
        float* dst = ws + (a2 == 0 ? OFF_KT : OFF_VT);
#pragma unroll
        for (int j = 0; j < 4; j++) {
            int ci = j * 256 + t;
            int np = ci >> 4, dp = ci & 15;
            float4 v;
            v.x = T[(a2 * 64 + dp * 4 + 0) * 65 + np];
            v.y = T[(a2 * 64 + dp * 4 + 1) * 65 + np];
            v.z = T[(a2 * 64 + dp * 4 + 2) * 65 + np];
            v.w = T[(a2 * 64 + dp * 4 + 3) * 65 + np];
            *(float4*)(dst + ((size_t)((b << 12) + n0 + np)) * 64 + dp * 4) = v;
        }
    }
}

// ---------------- KNN: wave-per-row, exact top-16 ----------------
template <int NK>
DEVI unsigned long long knn_row(const float4* base, float4 pn, int lane,
                                unsigned* out_row, unsigned long long* kept_worst) {
    unsigned long long arr[NK];
#pragma unroll
    for (int i = 0; i < NK; i++) arr[i] = ~0ull;
    float sqn = pn.w;
#pragma unroll 4
    for (int j = 0; j < 64; j++) {
        int m = (j << 6) + lane;
        float4 pm = base[m];
        float dot = __fadd_rn(__fadd_rn(__fmul_rn(pn.x, pm.x), __fmul_rn(pn.y, pm.y)),
                              __fmul_rn(pn.z, pm.z));
        float d2 = __fsub_rn(__fadd_rn(sqn, pm.w), __fmul_rn(2.0f, dot));
        unsigned ub = __float_as_uint(d2);
        ub = (ub >> 31) ? ~ub : (ub | 0x80000000u);
        unsigned long long key = ((unsigned long long)ub << 32) | (unsigned)m;
#pragma unroll
        for (int i = 0; i < NK; i++) {
            bool lt = key < arr[i];
            unsigned long long lo = lt ? key : arr[i];
            key = lt ? arr[i] : key;
            arr[i] = lo;
        }
    }
    unsigned long long kw = arr[NK - 1];
    unsigned long long v16 = 0;
    for (int r = 0; r < 16; r++) {
        unsigned long long mn = arr[0];
#pragma unroll
        for (int s = 1; s < 64; s <<= 1) {
            unsigned long long o = shflx64(mn, s);
            if (o < mn) mn = o;
        }
        if (arr[0] == mn) {
#pragma unroll
            for (int i = 0; i < NK - 1; i++) arr[i] = arr[i + 1];
            arr[NK - 1] = ~0ull;
            out_row[r] = (unsigned)(mn & 0xffffffffu);
        }
        v16 = mn;
    }
    *kept_worst = kw;
    return v16;
}

__global__ void knn_kernel(float* ws) {
    int t = threadIdx.x;
    int wid = t >> 6, lane = t & 63;
    int row = blockIdx.x * 4 + wid;
    int b = row >> 12;
    const float4* base = (const float4*)(ws + OFF_XYZS) + ((size_t)b << 12);
    float4 pn = base[row & 4095];
    unsigned* orow = (unsigned*)(ws + OFF_IDX) + (size_t)row * 16;

    unsigned long long kw;
    unsigned long long v16 = knn_row<6>(base, pn, lane, orow, &kw);
    if (__any(kw < v16)) {
        knn_row<16>(base, pn, lane, orow, &kw);
    }
}

// ---------------- fused main v3: R3 dataflow + waves_per_eu(2,2) register budget ----
// lane = (k 0..15) + 16*(nsub 0..3); wave handles 4 n's; block handles 16 n's.
// rpe[64] + X[64] + sim[64] all live (~215 regs) — max-occupancy capped at 2
// waves/EU so the allocator has the full 256-VGPR budget and does NOT spill.
__attribute__((amdgpu_waves_per_eu(2, 2)))
__global__ __launch_bounds__(256) void pt_main3(const float* __restrict__ ws,
                                                const void* __restrict__ points,
                                                void* __restrict__ out) {
    __shared__ float PL[64 * 16];   // points block-cols, [d][nl]
    __shared__ float QL[16 * 68];   // q rows, [nl][o] stride 68
    __shared__ float OUTS[64 * 16];

    int f32 = (int)((const unsigned*)ws)[OFF_FLAG];
    const float* wpack = ws + OFF_WPK;
    const float* wpos  = ws + OFF_WPOS;
    const float* b2p   = ws + OFF_B2;
    const float* bp2p  = ws + OFF_BP2;
    const float* wq    = ws + OFF_WQKV;
    const unsigned* idxws = (const unsigned*)(ws + OFF_IDX);
    const float4* xyzs = (const float4*)(ws + OFF_XYZS);

    int t = threadIdx.x;
    int wid = t >> 6, lane = t & 63;

    // XCD swizzle (proven: FETCH 39->13 MB): XCD x=bx&7 works on batch b=x&3 so
    // each XCD's 4 MB L2 holds exactly that batch's KT+VT (4 MB).
    int bx = blockIdx.x;               // grid 1024
    int x = bx & 7, j = bx >> 3;       // j in 0..127
    int b = x & 3;
    int n0 = ((((x >> 2) << 7) + j) << 4);   // ((x>>2)*128 + j) * 16

    // ---- phase 0a: stage this block's 16 point-columns into LDS (fp32)
    {
        int d = t >> 2, c4 = t & 3;
        size_t base = (size_t)(b * 64 + d) * NPTS + n0 + c4 * 4;
        if (f32) {
            float4 pv = *(const float4*)((const float*)points + base);
            PL[d * 16 + c4 * 4 + 0] = pv.x;
            PL[d * 16 + c4 * 4 + 1] = pv.y;
            PL[d * 16 + c4 * 4 + 2] = pv.z;
            PL[d * 16 + c4 * 4 + 3] = pv.w;
        } else {
            ushort4 pv = *(const ushort4*)((const unsigned short*)points + base);
            PL[d * 16 + c4 * 4 + 0] = us2f(pv.x);
            PL[d * 16 + c4 * 4 + 1] = us2f(pv.y);
            PL[d * 16 + c4 * 4 + 2] = us2f(pv.z);
            PL[d * 16 + c4 * 4 + 3] = us2f(pv.w);
        }
    }
    __syncthreads();

    // ---- phase 0b: q[nl][o] for the 16 n's (wave-uniform o, split-d partial dots)
    {
        int sg = lane >> 4, nl = lane & 15;
        for (int oi = 0; oi < 16; oi++) {
            int o = wid * 16 + oi;
            const float* wr = wq + o * 64 + sg * 16;
            float p = 0.f;
#pragma unroll
            for (int jj = 0; jj < 16; jj++) p = fmaf(wr[jj], PL[(sg * 16 + jj) * 16 + nl], p);
            p += __shfl_xor(p, 16, 64);
            p += __shfl_xor(p, 32, 64);
            if (lane < 16) QL[nl * 68 + o] = p;
        }
    }
    __syncthreads();

    // ---- per-lane task: (n, k)
    int k = lane & 15, nsub = lane >> 4;
    int nl = wid * 4 + nsub;
    int n = n0 + nl;
    int row = (b << 12) + n;
    unsigned m = idxws[(size_t)row * 16 + k] & 4095u;
    int mrow = (b << 12) + (int)m;

    float4 pn = xyzs[row];
    float4 pmx = xyzs[mrow];
    float rx = pn.x - pmx.x, ry = pn.y - pmx.y, rz = pn.z - pmx.z;

    // ---- pos MLP -> rpe[64] (stays live through the epilogue)
    float rpe[64];
#pragma unroll
    for (int d = 0; d < 64; d++) rpe[d] = bp2p[d];
#pragma unroll 2
    for (int o = 0; o < 64; o++) {
        const float* wr = wpos + o * 80;
        float hp = fmaf(wr[0], rx, fmaf(wr[1], ry, fmaf(wr[2], rz, wr[3])));
        hp = fmaxf(hp, 0.f);
#pragma unroll
        for (int d = 0; d < 64; d++) rpe[d] = fmaf(wr[4 + d], hp, rpe[d]);
    }

    // ---- X[64] = (q - k) + rpe
    float X[64];
    {
        const float4* q4 = (const float4*)(QL + nl * 68);
        const float4* kr = (const float4*)(ws + OFF_KT + (size_t)mrow * 64);
#pragma unroll
        for (int d4 = 0; d4 < 16; d4++) {
            float4 qv = q4[d4];
            float4 kv = kr[d4];
            X[4 * d4 + 0] = (qv.x - kv.x) + rpe[4 * d4 + 0];
            X[4 * d4 + 1] = (qv.y - kv.y) + rpe[4 * d4 + 1];
            X[4 * d4 + 2] = (qv.z - kv.z) + rpe[4 * d4 + 2];
            X[4 * d4 + 3] = (qv.w - kv.w) + rpe[4 * d4 + 3];
        }
    }

    // ---- att MLP: sim[d] = b2[d] + sum_o w2[d,o]*relu(w1[o,:]X + b1[o])
    float sim[64];
#pragma unroll
    for (int d = 0; d < 64; d++) sim[d] = b2p[d];
#pragma unroll 2
    for (int o = 0; o < 256; o++) {
        const float* wr = wpack + (size_t)o * 144;
        float h0 = 0.f, h1 = 0.f, h2 = 0.f, h3 = 0.f;
#pragma unroll
        for (int jj = 0; jj < 16; jj++) {
            h0 = fmaf(wr[jj],      X[jj],      h0);
            h1 = fmaf(wr[16 + jj], X[16 + jj], h1);
            h2 = fmaf(wr[32 + jj], X[32 + jj], h2);
            h3 = fmaf(wr[48 + jj], X[48 + jj], h3);
        }
        float h = ((h0 + h1) + (h2 + h3)) + wr[128];
        h = fmaxf(h, 0.f);
#pragma unroll
        for (int d = 0; d < 64; d++) sim[d] = fmaf(wr[64 + d], h, sim[d]);
    }

    // ---- softmax over k (16-lane groups) + agg = sum_k attn*(v + rpe)
    {
        const float4* vr = (const float4*)(ws + OFF_VT + (size_t)mrow * 64);
#pragma unroll
        for (int d4 = 0; d4 < 16; d4++) {
            float4 vv = vr[d4];
            float w4[4] = {vv.x + rpe[4 * d4 + 0], vv.y + rpe[4 * d4 + 1],
                           vv.z + rpe[4 * d4 + 2], vv.w + rpe[4 * d4 + 3]};
#pragma unroll
            for (int jj = 0; jj < 4; jj++) {
                int d = 4 * d4 + jj;
                float s = sim[d];
                float mx = s;
                mx = fmaxf(mx, __shfl_xor(mx, 1, 64));
                mx = fmaxf(mx, __shfl_xor(mx, 2, 64));
                mx = fmaxf(mx, __shfl_xor(mx, 4, 64));
                mx = fmaxf(mx, __shfl_xor(mx, 8, 64));
                float e = __expf(s - mx);
                float sm = e;
                sm += __shfl_xor(sm, 1, 64);
                sm += __shfl_xor(sm, 2, 64);
                sm += __shfl_xor(sm, 4, 64);
                sm += __shfl_xor(sm, 8, 64);
                float p = e * w4[jj];
                p += __shfl_xor(p, 1, 64);
                p += __shfl_xor(p, 2, 64);
                p += __shfl_xor(p, 4, 64);
                p += __shfl_xor(p, 8, 64);
                if (k == 0) OUTS[d * 16 + nl] = p / sm;
            }
        }
    }
    __syncthreads();

    // ---- coalesced store (dtype-dispatched)
    {
        int d = t >> 2, c = t & 3;
        float4 v = *(const float4*)&OUTS[d * 16 + c * 4];
        size_t ofs = (size_t)(b * 64 + d) * NPTS + n0 + c * 4;
        if (f32) {
            *(float4*)((float*)out + ofs) = v;
        } else {
            uint2 pk;
            pk.x = (unsigned)f2us(v.x) | ((unsigned)f2us(v.y) << 16);
            pk.y = (unsigned)f2us(v.z) | ((unsigned)f2us(v.w) << 16);
            *(uint2*)((unsigned short*)out + ofs) = pk;
        }
    }
}

// ---------------- fused main (compact fallback, !USE_KV) ----------------
__attribute__((amdgpu_waves_per_eu(2, 2)))
__global__ __launch_bounds__(256) void pt_main_compact(const float* __restrict__ ws,
                                                       const void* __restrict__ points,
                                                       void* __restrict__ out) {
    __shared__ float PL[64 * 16];
    __shared__ float QL[16 * 68];
    __shared__ float OUTS[64 * 16];

    int f32 = (int)((const unsigned*)ws)[OFF_FLAG];
    const float* wpack = ws + OFF_WPK;
    const float* wpos  = ws + OFF_WPOS;
    const float* b2p   = ws + OFF_B2;
    const float* bp2p  = ws + OFF_BP2;
    const float* wq    = ws + OFF_WQKV;
    const unsigned* idxws = (const unsigned*)(ws + OFF_IDX);
    const float4* xyzs = (const float4*)(ws + OFF_XYZS);

    int t = threadIdx.x;
    int wid = t >> 6, lane = t & 63;

    int bx = blockIdx.x;
    int x = bx & 7, j = bx >> 3;
    int b = x & 3;
    int n0 = ((((x >> 2) << 7) + j) << 4);

    {
        int d = t >> 2, c4 = t & 3;
        size_t base = (size_t)(b * 64 + d) * NPTS + n0 + c4 * 4;
        if (f32) {
            float4 pv = *(const float4*)((const float*)points + base);
            PL[d * 16 + c4 * 4 + 0] = pv.x;
            PL[d * 16 + c4 * 4 + 1] = pv.y;
            PL[d * 16 + c4 * 4 + 2] = pv.z;
            PL[d * 16 + c4 * 4 + 3] = pv.w;
        } else {
            ushort4 pv = *(const ushort4*)((const unsigned short*)points + base);
            PL[d * 16 + c4 * 4 + 0] = us2f(pv.x);
            PL[d * 16 + c4 * 4 + 1] = us2f(pv.y);
            PL[d * 16 + c4 * 4 + 2] = us2f(pv.z);
            PL[d * 16 + c4 * 4 + 3] = us2f(pv.w);
        }
    }
    __syncthreads();

    {
        int sg = lane >> 4, nl = lane & 15;
        for (int oi = 0; oi < 16; oi++) {
            int o = wid * 16 + oi;
            const float* wr = wq + o * 64 + sg * 16;
            float p = 0.f;
#pragma unroll
            for (int jj = 0; jj < 16; jj++) p = fmaf(wr[jj], PL[(sg * 16 + jj) * 16 + nl], p);
            p += __shfl_xor(p, 16, 64);
            p += __shfl_xor(p, 32, 64);
            if (lane < 16) QL[nl * 68 + o] = p;
        }
    }
    __syncthreads();

    int k = lane & 15, nsub = lane >> 4;
    int nl = wid * 4 + nsub;
    int n = n0 + nl;
    int row = (b << 12) + n;
    unsigned m = idxws[(size_t)row * 16 + k] & 4095u;

    float4 pn = xyzs[row];
    float4 pmx = xyzs[(b << 12) + (int)m];
    float rx = pn.x - pmx.x, ry = pn.y - pmx.y, rz = pn.z - pmx.z;

    float rpe[64];
#pragma unroll
    for (int d = 0; d < 64; d++) rpe[d] = bp2p[d];
#pragma unroll 2
    for (int o = 0; o < 64; o++) {
        const float* wr = wpos + o * 80;
        float hp = fmaf(wr[0], rx, fmaf(wr[1], ry, fmaf(wr[2], rz, wr[3])));
        hp = fmaxf(hp, 0.f);
#pragma unroll
        for (int d = 0; d < 64; d++) rpe[d] = fmaf(wr[4 + d], hp, rpe[d]);
    }

    float Pm[64];
#pragma unroll
    for (int d = 0; d < 64; d++)
        Pm[d] = ldin(points, ((size_t)(b * 64 + d) << 12) + (int)m, f32);

    float X[64];
    {
        const float* qrow = QL + nl * 68;
#pragma unroll 2
        for (int d = 0; d < 64; d++) {
            const float* wr = wq + (64 + d) * 64;
            float kd = 0.f;
#pragma unroll
            for (int dd = 0; dd < 64; dd++) kd = fmaf(wr[dd], Pm[dd], kd);
            X[d] = (qrow[d] - kd) + rpe[d];
        }
    }

    float sim[64];
#pragma unroll
    for (int d = 0; d < 64; d++) sim[d] = b2p[d];
#pragma unroll 2
    for (int o = 0; o < 256; o++) {
        const float* wr = wpack + (size_t)o * 144;
        float h0 = 0.f, h1 = 0.f, h2 = 0.f, h3 = 0.f;
#pragma unroll
        for (int jj = 0; jj < 16; jj++) {
            h0 = fmaf(wr[jj],      X[jj],      h0);
            h1 = fmaf(wr[16 + jj], X[16 + jj], h1);
            h2 = fmaf(wr[32 + jj], X[32 + jj], h2);
            h3 = fmaf(wr[48 + jj], X[48 + jj], h3);
        }
        float h = ((h0 + h1) + (h2 + h3)) + wr[128];
        h = fmaxf(h, 0.f);
#pragma unroll
        for (int d = 0; d < 64; d++) sim[d] = fmaf(wr[64 + d], h, sim[d]);
    }

    {
#pragma unroll
        for (int d4 = 0; d4 < 16; d4++) {
            float vvv[4];
#pragma unroll
            for (int jj = 0; jj < 4; jj++) {
                int d = 4 * d4 + jj;
                const float* wrv = wq + (128 + d) * 64;
                float vd = 0.f;
#pragma unroll
                for (int dd = 0; dd < 64; dd++) vd = fmaf(wrv[dd], Pm[dd], vd);
                vvv[jj] = vd + rpe[d];
            }
#pragma unroll
            for (int jj = 0; jj < 4; jj++) {
                int d = 4 * d4 + jj;
                float s = sim[d];
                float mx = s;
                mx = fmaxf(mx, __shfl_xor(mx, 1, 64));
                mx = fmaxf(mx, __shfl_xor(mx, 2, 64));
                mx = fmaxf(mx, __shfl_xor(mx, 4, 64));
                mx = fmaxf(mx, __shfl_xor(mx, 8, 64));
                float e = __expf(s - mx);
                float sm = e;
                sm += __shfl_xor(sm, 1, 64);
                sm += __shfl_xor(sm, 2, 64);
                sm += __shfl_xor(sm, 4, 64);
                sm += __shfl_xor(sm, 8, 64);
                float p = e * vvv[jj];
                p += __shfl_xor(p, 1, 64);
                p += __shfl_xor(p, 2, 64);
                p += __shfl_xor(p, 4, 64);
                p += __shfl_xor(p, 8, 64);
                if (k == 0) OUTS[d * 16 + nl] = p / sm;
            }
        }
    }
    __syncthreads();

    {
        int d = t >> 2, c = t & 3;
        float4 v = *(const float4*)&OUTS[d * 16 + c * 4];
        size_t ofs = (size_t)(b * 64 + d) * NPTS + n0 + c * 4;
        if (f32) {
            *(float4*)((float*)out + ofs) = v;
        } else {
            uint2 pk;
            pk.x = (unsigned)f2us(v.x) | ((unsigned)f2us(v.y) << 16);
            pk.y = (unsigned)f2us(v.z) | ((unsigned)f2us(v.w) << 16);
            *(uint2*)((unsigned short*)out + ofs) = pk;
        }
    }
}

// ---------------- host ----------------
extern "C" void kernel_launch(void* const* d_in, const int* in_sizes, int n_in,
                              void* d_out, int out_size, void* d_ws, size_t ws_size,
                              hipStream_t stream) {
    const void* xyz    = d_in[0];
    const void* points = d_in[1];
    const void* w_qkv  = d_in[2];
    const void* w_pos1 = d_in[3];
    const void* b_pos1 = d_in[4];
    const void* w_pos2 = d_in[5];
    const void* b_pos2 = d_in[6];
    const void* w_att1 = d_in[7];
    const void* b_att1 = d_in[8];
    const void* w_att2 = d_in[9];
    const void* b_att2 = d_in[10];
    float* ws = (float*)d_ws;

    bool use_kv = ws_size >= FULL_FLOATS * sizeof(float);

    hipLaunchKernelGGL(detect_kernel, dim3(1), dim3(256), 0, stream,
                       xyz, (unsigned*)ws + OFF_FLAG);
    hipLaunchKernelGGL(prep_kernel, dim3(66), dim3(256), 0, stream,
                       xyz, w_qkv, w_pos1, b_pos1, w_pos2, b_pos2,
                       w_att1, b_att1, w_att2, b_att2, ws);
    if (use_kv)
        hipLaunchKernelGGL(kv_kernel, dim3(256), dim3(256), 0, stream, points, ws);
    hipLaunchKernelGGL(knn_kernel, dim3(4096), dim3(256), 0, stream, ws);
    if (use_kv)
        hipLaunchKernelGGL(pt_main3, dim3(1024), dim3(256), 0, stream, (const float*)ws, points, d_out);
    else
        hipLaunchKernelGGL(pt_main_compact, dim3(1024), dim3(256), 0, stream, (const float*)ws, points, d_out);
}

// Round 7
// 474.889 us; speedup vs baseline: 2.7405x; 2.0786x over previous
//
#include <hip/hip_runtime.h>
#include <hip/hip_bf16.h>
#include <stdint.h>

#define DEVI static __device__ __forceinline__

typedef unsigned short ushort_t;
typedef __attribute__((ext_vector_type(8))) short s8v;   // 8 bf16 (4 VGPRs)
typedef __attribute__((ext_vector_type(4))) float f4v;   // MFMA C/D

// Problem constants
constexpr int NPTS = 4096;     // N
constexpr int BN   = 16384;    // B*N

// ---------------- ws layout (float offsets) ----------------
constexpr size_t OFF_FLAG = 0;                          // unsigned flag (1=fp32 inputs)
constexpr size_t OFF_XYZS = 16;                         // float4[BN]  (x,y,z,sq)
constexpr size_t OFF_WPK  = OFF_XYZS + 65536;           // float[256*144] att-MLP pack (compact path)
constexpr size_t OFF_WPOS = OFF_WPK + 256 * 144;        // float[64*80] pos-MLP pack
constexpr size_t OFF_B2   = OFF_WPOS + 64 * 80;         // float[64] b_att2
constexpr size_t OFF_BP2  = OFF_B2 + 64;                // float[64] b_pos2
constexpr size_t OFF_WQKV = OFF_BP2 + 64;               // float[192*64]
constexpr size_t OFF_IDX  = OFF_WQKV + 192 * 64;        // uint[BN*16]
constexpr size_t OFF_KT   = OFF_IDX + (size_t)BN * 16;  // float[BN*64]
constexpr size_t OFF_VT   = OFF_KT + (size_t)BN * 64;   // float[BN*64]
// split-bf16 weight packs (ushort region), offsets in shorts:
constexpr size_t OFF_WSPL = OFF_VT + (size_t)BN * 64;   // base (float units)
constexpr size_t U_W1H = 0;          // [256][64]
constexpr size_t U_W1L = 16384;
constexpr size_t U_W2H = 32768;      // [64][256]
constexpr size_t U_W2L = 49152;
constexpr size_t U_WP2H = 65536;     // [64][64]
constexpr size_t U_WP2L = 69632;     // end 73728 shorts = 36864 floats
constexpr size_t OFF_B1   = OFF_WSPL + 36864;           // float[256]
constexpr size_t OFF_WP1B = OFF_B1 + 256;               // float[64][4] = {w1x,w1y,w1z,b1}
constexpr size_t FULL_FLOATS = OFF_WP1B + 256;          // ~10.07 MB

DEVI float b2f(__hip_bfloat16 h) { return __bfloat162float(h); }

DEVI float us2f(ushort_t u) {
    __hip_bfloat16 h;
    *(ushort_t*)&h = u;
    return __bfloat162float(h);
}

DEVI ushort_t f2us(float f) {
    __hip_bfloat16 h = __float2bfloat16(f);
    return *(ushort_t*)&h;
}

DEVI float ldin(const void* p, size_t i, int f32) {
    return f32 ? ((const float*)p)[i] : b2f(((const __hip_bfloat16*)p)[i]);
}

// split fp32 -> (hi, lo) bf16 pair; hi+lo reconstructs x to ~2^-18 rel
DEVI void split1(float x, ushort_t* h, ushort_t* l) {
    __hip_bfloat16 bh = __float2bfloat16(x);
    float r = x - __bfloat162float(bh);
    __hip_bfloat16 bl = __float2bfloat16(r);
    *h = *(ushort_t*)&bh;
    *l = *(ushort_t*)&bl;
}

DEVI f4v MF(s8v a, s8v b, f4v c) {
    return __builtin_amdgcn_mfma_f32_16x16x32_bf16(a, b, c, 0, 0, 0);
}

DEVI unsigned long long shflx64(unsigned long long v, int m) {
    unsigned lo = __shfl_xor((unsigned)(v & 0xffffffffull), m, 64);
    unsigned hi = __shfl_xor((unsigned)(v >> 32), m, 64);
    return ((unsigned long long)hi << 32) | lo;
}

// ---------------- dtype detector ----------------
__global__ void detect_kernel(const void* xyz, unsigned* flagp) {
    __shared__ int s;
    int t = threadIdx.x;
    if (t == 0) s = 0;
    __syncthreads();
    const ushort_t* u = (const ushort_t*)xyz;
    int cnt = 0;
    for (int i = t; i < 2048; i += 256) {
        unsigned e = (u[i] >> 7) & 0xFFu;
        cnt += (e >= 140u);
    }
    atomicAdd(&s, cnt);
    __syncthreads();
    if (t == 0) *flagp = (s > 16) ? 1u : 0u;
}

// ---------------- prep ----------------
__global__ void prep_kernel(const void* xyz, const void* w_qkv,
                            const void* w_pos1, const void* b_pos1,
                            const void* w_pos2, const void* b_pos2,
                            const void* w_att1, const void* b_att1,
                            const void* w_att2, const void* b_att2,
                            float* ws, int use_kv) {
    int f32 = (int)((const unsigned*)ws)[OFF_FLAG];
    int t = threadIdx.x;
    int blk = blockIdx.x;
    if (blk == 0) {
        float* wp = ws + OFF_WPK + (size_t)t * 144;
        for (int d = 0; d < 64; d++) wp[d]      = ldin(w_att1, t * 64 + d, f32);
        for (int d = 0; d < 64; d++) wp[64 + d] = ldin(w_att2, d * 256 + t, f32);
        wp[128] = ldin(b_att1, t, f32);
    } else if (blk == 1) {
        if (t < 64) {
            float* wp = ws + OFF_WPOS + (size_t)t * 80;
            wp[0] = ldin(w_pos1, t * 3 + 0, f32);
            wp[1] = ldin(w_pos1, t * 3 + 1, f32);
            wp[2] = ldin(w_pos1, t * 3 + 2, f32);
            wp[3] = ldin(b_pos1, t, f32);
            for (int d = 0; d < 64; d++) wp[4 + d] = ldin(w_pos2, d * 64 + t, f32);
            ws[OFF_B2 + t]  = ldin(b_att2, t, f32);
            ws[OFF_BP2 + t] = ldin(b_pos2, t, f32);
        }
        for (int i = t; i < 192 * 64; i += 256) ws[OFF_WQKV + i] = ldin(w_qkv, i, f32);
    } else if (blk < 66) {
        int gid = (blk - 2) * 256 + t;   // 0..16383
        int b = gid >> 12, n = gid & 4095;
        float x = ldin(xyz, (size_t)(b * 3 + 0) * NPTS + n, f32);
        float y = ldin(xyz, (size_t)(b * 3 + 1) * NPTS + n, f32);
        float z = ldin(xyz, (size_t)(b * 3 + 2) * NPTS + n, f32);
        float sq = __fadd_rn(__fadd_rn(__fmul_rn(x, x), __fmul_rn(y, y)), __fmul_rn(z, z));
        ((float4*)(ws + OFF_XYZS))[gid] = make_float4(x, y, z, sq);
    } else if (blk == 66) {
        if (!use_kv) return;
        // W1 split [256][64] row-major + b1
        ushort_t* wsp = (ushort_t*)(ws + OFF_WSPL);
        for (int d = 0; d < 64; d++)
            split1(ldin(w_att1, t * 64 + d, f32), &wsp[U_W1H + t * 64 + d], &wsp[U_W1L + t * 64 + d]);
        ws[OFF_B1 + t] = ldin(b_att1, t, f32);
    } else {
        if (!use_kv) return;
        ushort_t* wsp = (ushort_t*)(ws + OFF_WSPL);
        for (int i = t; i < 64 * 256; i += 256)   // W2 [64][256]
            split1(ldin(w_att2, i, f32), &wsp[U_W2H + i], &wsp[U_W2L + i]);
        for (int i = t; i < 64 * 64; i += 256)    // Wp2 [64][64]
            split1(ldin(w_pos2, i, f32), &wsp[U_WP2H + i], &wsp[U_WP2L + i]);
        if (t < 64) {                              // wp1b [64][4]
            ws[OFF_WP1B + t * 4 + 0] = ldin(w_pos1, t * 3 + 0, f32);
            ws[OFF_WP1B + t * 4 + 1] = ldin(w_pos1, t * 3 + 1, f32);
            ws[OFF_WP1B + t * 4 + 2] = ldin(w_pos1, t * 3 + 2, f32);
            ws[OFF_WP1B + t * 4 + 3] = ldin(b_pos1, t, f32);
        }
    }
}

// ---------------- kv GEMM: kt/vt row-major [n][d], fp32 ----------------
__global__ void kv_kernel(const void* points, float* ws) {
    __shared__ float T[128 * 65];
    int f32 = (int)((const unsigned*)ws)[OFF_FLAG];
    const float* wq = ws + OFF_WQKV + 64 * 64;  // rows 64..191 (k then v)
    int t = threadIdx.x;
    int wid = __builtin_amdgcn_readfirstlane(t >> 6);
    int lane = t & 63;
    int b = blockIdx.x >> 6;
    int n0 = (blockIdx.x & 63) * 64;

    float P[64];
#pragma unroll
    for (int d = 0; d < 64; d++)
        P[d] = ldin(points, (size_t)(b * 64 + d) * NPTS + n0 + lane, f32);

    for (int i = 0; i < 32; i++) {
        int o = wid + 4 * i;
        const float* wr = wq + o * 64;
        float acc = 0.f;
#pragma unroll
        for (int d = 0; d < 64; d++) acc = fmaf(wr[d], P[d], acc);
        T[o * 65 + lane] = acc;
    }
    __syncthreads();

#pragma unroll
    for (int a2 = 0; a2 < 2; a2++) {
        float* dst = ws + (a2 == 0 ? OFF_KT : OFF_VT);
#pragma unroll
        for (int j = 0; j < 4; j++) {
            int ci = j * 256 + t;
            int np = ci >> 4, dp = ci & 15;
            float4 v;
            v.x = T[(a2 * 64 + dp * 4 + 0) * 65 + np];
            v.y = T[(a2 * 64 + dp * 4 + 1) * 65 + np];
            v.z = T[(a2 * 64 + dp * 4 + 2) * 65 + np];
            v.w = T[(a2 * 64 + dp * 4 + 3) * 65 + np];
            *(float4*)(dst + ((size_t)((b << 12) + n0 + np)) * 64 + dp * 4) = v;
        }
    }
}

// ---------------- KNN: wave-per-row, exact top-16 ----------------
template <int NK>
DEVI unsigned long long knn_row(const float4* base, float4 pn, int lane,
                                unsigned* out_row, unsigned long long* kept_worst) {
    unsigned long long arr[NK];
#pragma unroll
    for (int i = 0; i < NK; i++) arr[i] = ~0ull;
    float sqn = pn.w;
#pragma unroll 4
    for (int j = 0; j < 64; j++) {
        int m = (j << 6) + lane;
        float4 pm = base[m];
        float dot = __fadd_rn(__fadd_rn(__fmul_rn(pn.x, pm.x), __fmul_rn(pn.y, pm.y)),
                              __fmul_rn(pn.z, pm.z));
        float d2 = __fsub_rn(__fadd_rn(sqn, pm.w), __fmul_rn(2.0f, dot));
        unsigned ub = __float_as_uint(d2);
        ub = (ub >> 31) ? ~ub : (ub | 0x80000000u);
        unsigned long long key = ((unsigned long long)ub << 32) | (unsigned)m;
#pragma unroll
        for (int i = 0; i < NK; i++) {
            bool lt = key < arr[i];
            unsigned long long lo = lt ? key : arr[i];
            key = lt ? arr[i] : key;
            arr[i] = lo;
        }
    }
    unsigned long long kw = arr[NK - 1];
    unsigned long long v16 = 0;
    for (int r = 0; r < 16; r++) {
        unsigned long long mn = arr[0];
#pragma unroll
        for (int s = 1; s < 64; s <<= 1) {
            unsigned long long o = shflx64(mn, s);
            if (o < mn) mn = o;
        }
        if (arr[0] == mn) {
#pragma unroll
            for (int i = 0; i < NK - 1; i++) arr[i] = arr[i + 1];
            arr[NK - 1] = ~0ull;
            out_row[r] = (unsigned)(mn & 0xffffffffu);
        }
        v16 = mn;
    }
    *kept_worst = kw;
    return v16;
}

__global__ void knn_kernel(float* ws) {
    int t = threadIdx.x;
    int wid = t >> 6, lane = t & 63;
    int row = blockIdx.x * 4 + wid;
    int b = row >> 12;
    const float4* base = (const float4*)(ws + OFF_XYZS) + ((size_t)b << 12);
    float4 pn = base[row & 4095];
    unsigned* orow = (unsigned*)(ws + OFF_IDX) + (size_t)row * 16;

    unsigned long long kw;
    unsigned long long v16 = knn_row<6>(base, pn, lane, orow, &kw);
    if (__any(kw < v16)) {
        knn_row<16>(base, pn, lane, orow, &kw);
    }
}

// ---------------- fused main, MFMA version ----------------
// Block: 8 n's -> 128 columns c = nl*16 + k. 4 waves; wave w owns n-tiles {2w,2w+1}.
// Verified 16x16x32 bf16 layouts: A[m=lane&15][k=quad*8+j]; B[n=lane&15][k=quad*8+j];
// C/D: col n = lane&15, row m = quad*4+reg. Split-bf16 3-product => fp32-accurate GEMMs.
__global__ __launch_bounds__(256, 2) void pt_mfma(const float* __restrict__ ws,
                                                  const void* __restrict__ points,
                                                  void* __restrict__ out) {
    __shared__ ushort_t XH[128][72];   // X hi (also pos-hidden Hp hi before phase 2)
    __shared__ ushort_t XL[128][72];   // X lo (also Hp lo)
    __shared__ ushort_t HTH[128][40];  // hidden o-tile hi (o-tile = 32)
    __shared__ ushort_t HTL[128][40];
    __shared__ float PL[64][9];        // points cols [d][nl]
    __shared__ float QL[8][68];        // q rows [nl][d]
    __shared__ float OUTS[64][8];

    int f32 = (int)((const unsigned*)ws)[OFF_FLAG];
    const float* KTp  = ws + OFF_KT;
    const float* VTp  = ws + OFF_VT;
    const float* wq   = ws + OFF_WQKV;
    const float* b1p  = ws + OFF_B1;
    const float* b2p  = ws + OFF_B2;
    const float* bp2p = ws + OFF_BP2;
    const float* wp1b = ws + OFF_WP1B;
    const ushort_t* wsp = (const ushort_t*)(ws + OFF_WSPL);
    const ushort_t* w1h = wsp + U_W1H;
    const ushort_t* w1l = wsp + U_W1L;
    const ushort_t* w2h = wsp + U_W2H;
    const ushort_t* w2l = wsp + U_W2L;
    const ushort_t* wp2h = wsp + U_WP2H;
    const ushort_t* wp2l = wsp + U_WP2L;
    const unsigned* idxp = (const unsigned*)(ws + OFF_IDX);
    const float4* xyzs = (const float4*)(ws + OFF_XYZS);

    int t = threadIdx.x;
    int w = t >> 6, lane = t & 63;
    int cl = lane & 15, quad = lane >> 4;

    // XCD swizzle: XCD x = bx&7 handles batch b = x&3 (KT+VT of one batch = 2 MB -> one L2)
    int bx = blockIdx.x;                    // grid 2048
    int x = bx & 7;
    int b = x & 3;
    int n0 = (((x >> 2) << 8) + (bx >> 3)) << 3;   // ((x>>2)*256 + j) * 8

    // ---- phase 0a: stage 8 point-columns into LDS
    {
        int d = t >> 2, c2 = (t & 3) * 2;
        size_t base = (size_t)(b * 64 + d) * NPTS + n0 + c2;
        if (f32) {
            float2 pv = *(const float2*)((const float*)points + base);
            PL[d][c2] = pv.x; PL[d][c2 + 1] = pv.y;
        } else {
            ushort2 pv = *(const ushort2*)((const ushort_t*)points + base);
            PL[d][c2] = us2f(pv.x); PL[d][c2 + 1] = us2f(pv.y);
        }
    }
    __syncthreads();

    // ---- phase 0b: q[nl][d] (8 n x 64 d) VALU
    {
        int nl = lane & 7, sg = lane >> 3;
        for (int oi = 0; oi < 16; oi++) {
            int o = w * 16 + oi;
            const float* wr = wq + o * 64 + sg * 8;
            float p = 0.f;
#pragma unroll
            for (int j = 0; j < 8; j++) p = fmaf(wr[j], PL[sg * 8 + j][nl], p);
            p += __shfl_xor(p, 8, 64);
            p += __shfl_xor(p, 16, 64);
            p += __shfl_xor(p, 32, 64);
            if (lane < 8) QL[nl][o] = p;
        }
    }

    // ---- phase 0c: pos-MLP hidden Hp[c][h] (split bf16) into XH/XL region
    {
        int c = t >> 1, hh = (t & 1) * 32;
        int nl = c >> 4, kk = c & 15;
        int row = (b << 12) + n0 + nl;
        unsigned m = idxp[(size_t)row * 16 + kk] & 4095u;
        float4 pn = xyzs[row];
        float4 pm = xyzs[(b << 12) + (int)m];
        float rx = pn.x - pm.x, ry = pn.y - pm.y, rz = pn.z - pm.z;
#pragma unroll 4
        for (int h2 = 0; h2 < 32; h2 += 2) {
            ushort_t hA, lA, hB, lB;
            float4 wA = *(const float4*)(wp1b + (size_t)(hh + h2) * 4);
            float4 wB = *(const float4*)(wp1b + (size_t)(hh + h2 + 1) * 4);
            float vA = fmaxf(fmaf(wA.x, rx, fmaf(wA.y, ry, fmaf(wA.z, rz, wA.w))), 0.f);
            float vB = fmaxf(fmaf(wB.x, rx, fmaf(wB.y, ry, fmaf(wB.z, rz, wB.w))), 0.f);
            split1(vA, &hA, &lA);
            split1(vB, &hB, &lB);
            *(unsigned*)&XH[c][hh + h2] = (unsigned)hA | ((unsigned)hB << 16);
            *(unsigned*)&XL[c][hh + h2] = (unsigned)lA | ((unsigned)lB << 16);
        }
    }
    __syncthreads();

    // ---- phase 1: P2 MFMA  rpe[d][c] = Wp2 * Hp  (+ bp2)
    f4v rpe[2][4];
#pragma unroll
    for (int i = 0; i < 2; i++)
#pragma unroll
        for (int j = 0; j < 4; j++) rpe[i][j] = {0.f, 0.f, 0.f, 0.f};

#pragma unroll
    for (int s = 0; s < 2; s++) {
        s8v bh[2], bl[2];
#pragma unroll
        for (int nti = 0; nti < 2; nti++) {
            int c = (2 * w + nti) * 16 + cl;
            bh[nti] = *(const s8v*)&XH[c][s * 32 + quad * 8];
            bl[nti] = *(const s8v*)&XL[c][s * 32 + quad * 8];
        }
#pragma unroll
        for (int dt = 0; dt < 4; dt++) {
            const ushort_t* ap = wp2h + (size_t)(dt * 16 + cl) * 64 + s * 32 + quad * 8;
            const ushort_t* alp = wp2l + (size_t)(dt * 16 + cl) * 64 + s * 32 + quad * 8;
            s8v ah = *(const s8v*)ap;
            s8v al = *(const s8v*)alp;
#pragma unroll
            for (int nti = 0; nti < 2; nti++) {
                rpe[nti][dt] = MF(ah, bh[nti], rpe[nti][dt]);
                rpe[nti][dt] = MF(ah, bl[nti], rpe[nti][dt]);
                rpe[nti][dt] = MF(al, bh[nti], rpe[nti][dt]);
            }
        }
    }
    // + bp2
#pragma unroll
    for (int dt = 0; dt < 4; dt++) {
        float4 bv = *(const float4*)(bp2p + dt * 16 + quad * 4);
#pragma unroll
        for (int nti = 0; nti < 2; nti++) {
            rpe[nti][dt][0] += bv.x; rpe[nti][dt][1] += bv.y;
            rpe[nti][dt][2] += bv.z; rpe[nti][dt][3] += bv.w;
        }
    }
    __syncthreads();   // all P2 reads of Hp done before X overwrites region

    // ---- phase 2: build X = (q - k) + rpe, split bf16 into XH/XL
#pragma unroll
    for (int nti = 0; nti < 2; nti++) {
        int nt = 2 * w + nti;
        int c = nt * 16 + cl;
        int row = (b << 12) + n0 + nt;
        unsigned m = idxp[(size_t)row * 16 + cl] & 4095u;
        int mrow = (b << 12) + (int)m;
#pragma unroll
        for (int dt = 0; dt < 4; dt++) {
            int d0 = dt * 16 + quad * 4;
            float4 q4 = *(const float4*)&QL[nt][d0];
            float4 k4 = *(const float4*)(KTp + (size_t)mrow * 64 + d0);
            float xv[4];
            xv[0] = (q4.x - k4.x) + rpe[nti][dt][0];
            xv[1] = (q4.y - k4.y) + rpe[nti][dt][1];
            xv[2] = (q4.z - k4.z) + rpe[nti][dt][2];
            xv[3] = (q4.w - k4.w) + rpe[nti][dt][3];
            ushort_t hh[4], ll[4];
#pragma unroll
            for (int r = 0; r < 4; r++) split1(xv[r], &hh[r], &ll[r]);
            uint2 H2, L2x;
            H2.x = (unsigned)hh[0] | ((unsigned)hh[1] << 16);
            H2.y = (unsigned)hh[2] | ((unsigned)hh[3] << 16);
            L2x.x = (unsigned)ll[0] | ((unsigned)ll[1] << 16);
            L2x.y = (unsigned)ll[2] | ((unsigned)ll[3] << 16);
            *(uint2*)&XH[c][d0] = H2;
            *(uint2*)&XL[c][d0] = L2x;
        }
    }
    __syncthreads();

    // ---- phase 3: o-tile loop (8 tiles of 32 o): L1 -> HT -> L2 accumulate sim
    f4v sim[2][4];
#pragma unroll
    for (int i = 0; i < 2; i++)
#pragma unroll
        for (int j = 0; j < 4; j++) sim[i][j] = {0.f, 0.f, 0.f, 0.f};

    for (int ot = 0; ot < 8; ot++) {
        // L1: H-tile [32 o][128 c] = W1[o-tile] * X
        f4v hacc[2][2];
#pragma unroll
        for (int i = 0; i < 2; i++)
#pragma unroll
            for (int j = 0; j < 2; j++) hacc[i][j] = {0.f, 0.f, 0.f, 0.f};
#pragma unroll
        for (int s = 0; s < 2; s++) {
            s8v bh[2], bl[2];
#pragma unroll
            for (int nti = 0; nti < 2; nti++) {
                int c = (2 * w + nti) * 16 + cl;
                bh[nti] = *(const s8v*)&XH[c][s * 32 + quad * 8];
                bl[nti] = *(const s8v*)&XL[c][s * 32 + quad * 8];
            }
#pragma unroll
            for (int mt = 0; mt < 2; mt++) {
                int orow = ot * 32 + mt * 16 + cl;
                s8v ah = *(const s8v*)(w1h + (size_t)orow * 64 + s * 32 + quad * 8);
                s8v al = *(const s8v*)(w1l + (size_t)orow * 64 + s * 32 + quad * 8);
#pragma unroll
                for (int nti = 0; nti < 2; nti++) {
                    hacc[mt][nti] = MF(ah, bh[nti], hacc[mt][nti]);
                    hacc[mt][nti] = MF(ah, bl[nti], hacc[mt][nti]);
                    hacc[mt][nti] = MF(al, bh[nti], hacc[mt][nti]);
                }
            }
        }
        // bias + relu + split -> HT
#pragma unroll
        for (int mt = 0; mt < 2; mt++) {
            int o0 = ot * 32 + mt * 16 + quad * 4;
            float4 bv = *(const float4*)(b1p + o0);
#pragma unroll
            for (int nti = 0; nti < 2; nti++) {
                int c = (2 * w + nti) * 16 + cl;
                float hv[4];
                hv[0] = fmaxf(hacc[mt][nti][0] + bv.x, 0.f);
                hv[1] = fmaxf(hacc[mt][nti][1] + bv.y, 0.f);
                hv[2] = fmaxf(hacc[mt][nti][2] + bv.z, 0.f);
                hv[3] = fmaxf(hacc[mt][nti][3] + bv.w, 0.f);
                ushort_t hh[4], ll[4];
#pragma unroll
                for (int r = 0; r < 4; r++) split1(hv[r], &hh[r], &ll[r]);
                uint2 H2, L2x;
                H2.x = (unsigned)hh[0] | ((unsigned)hh[1] << 16);
                H2.y = (unsigned)hh[2] | ((unsigned)hh[3] << 16);
                L2x.x = (unsigned)ll[0] | ((unsigned)ll[1] << 16);
                L2x.y = (unsigned)ll[2] | ((unsigned)ll[3] << 16);
                int ol = mt * 16 + quad * 4;
                *(uint2*)&HTH[c][ol] = H2;
                *(uint2*)&HTL[c][ol] = L2x;
            }
        }
        __syncthreads();
        // L2 partial: sim += W2[:, o-tile] * HT   (K=32, one k-step)
        {
            s8v bh[2], bl[2];
#pragma unroll
            for (int nti = 0; nti < 2; nti++) {
                int c = (2 * w + nti) * 16 + cl;
                bh[nti] = *(const s8v*)&HTH[c][quad * 8];
                bl[nti] = *(const s8v*)&HTL[c][quad * 8];
            }
#pragma unroll
            for (int dt = 0; dt < 4; dt++) {
                s8v ah = *(const s8v*)(w2h + (size_t)(dt * 16 + cl) * 256 + ot * 32 + quad * 8);
                s8v al = *(const s8v*)(w2l + (size_t)(dt * 16 + cl) * 256 + ot * 32 + quad * 8);
#pragma unroll
                for (int nti = 0; nti < 2; nti++) {
                    sim[nti][dt] = MF(ah, bh[nti], sim[nti][dt]);
                    sim[nti][dt] = MF(ah, bl[nti], sim[nti][dt]);
                    sim[nti][dt] = MF(al, bh[nti], sim[nti][dt]);
                }
            }
        }
        __syncthreads();   // before next o-tile overwrites HT
    }

    // ---- phase 4: softmax over k (cl-groups) + agg = sum_k attn*(v + rpe)
#pragma unroll
    for (int nti = 0; nti < 2; nti++) {
        int nt = 2 * w + nti;
        int row = (b << 12) + n0 + nt;
        unsigned m = idxp[(size_t)row * 16 + cl] & 4095u;
        int mrow = (b << 12) + (int)m;
#pragma unroll
        for (int dt = 0; dt < 4; dt++) {
            int d0 = dt * 16 + quad * 4;
            float4 b2v = *(const float4*)(b2p + d0);
            float4 v4 = *(const float4*)(VTp + (size_t)mrow * 64 + d0);
            float bb[4] = {b2v.x, b2v.y, b2v.z, b2v.w};
            float vv[4] = {v4.x, v4.y, v4.z, v4.w};
#pragma unroll
            for (int r = 0; r < 4; r++) {
                float s = sim[nti][dt][r] + bb[r];
                float mx = s;
                mx = fmaxf(mx, __shfl_xor(mx, 1, 64));
                mx = fmaxf(mx, __shfl_xor(mx, 2, 64));
                mx = fmaxf(mx, __shfl_xor(mx, 4, 64));
                mx = fmaxf(mx, __shfl_xor(mx, 8, 64));
                float e = __expf(s - mx);
                float sm = e;
                sm += __shfl_xor(sm, 1, 64);
                sm += __shfl_xor(sm, 2, 64);
                sm += __shfl_xor(sm, 4, 64);
                sm += __shfl_xor(sm, 8, 64);
                float p = e * (vv[r] + rpe[nti][dt][r]);
                p += __shfl_xor(p, 1, 64);
                p += __shfl_xor(p, 2, 64);
                p += __shfl_xor(p, 4, 64);
                p += __shfl_xor(p, 8, 64);
                if (cl == 0) OUTS[d0 + r][nt] = p / sm;
            }
        }
    }
    __syncthreads();

    // ---- coalesced store
    {
        int d = t >> 2, c2 = (t & 3) * 2;
        float a = OUTS[d][c2], bb = OUTS[d][c2 + 1];
        size_t ofs = (size_t)(b * 64 + d) * NPTS + n0 + c2;
        if (f32) {
            float2 v = {a, bb};
            *(float2*)((float*)out + ofs) = v;
        } else {
            unsigned pk = (unsigned)f2us(a) | ((unsigned)f2us(bb) << 16);
            *(unsigned*)((ushort_t*)out + ofs) = pk;
        }
    }
}

// ---------------- fused main (compact fallback, !use_kv) — unchanged R6 path ----------------
__global__ __launch_bounds__(256, 2) void pt_main_compact(const float* __restrict__ ws,
                                                          const void* __restrict__ points,
                                                          void* __restrict__ out) {
    __shared__ float PL[64 * 16];
    __shared__ float QL[16 * 68];
    __shared__ float OUTS[64 * 16];

    int f32 = (int)((const unsigned*)ws)[OFF_FLAG];
    const float* wpack = ws + OFF_WPK;
    const float* wpos  = ws + OFF_WPOS;
    const float* b2p   = ws + OFF_B2;
    const float* bp2p  = ws + OFF_BP2;
    const float* wq    = ws + OFF_WQKV;
    const unsigned* idxws = (const unsigned*)(ws + OFF_IDX);
    const float4* xyzs = (const float4*)(ws + OFF_XYZS);

    int t = threadIdx.x;
    int wid = t >> 6, lane = t & 63;

    int bx = blockIdx.x;
    int x = bx & 7, j = bx >> 3;
    int b = x & 3;
    int n0 = ((((x >> 2) << 7) + j) << 4);

    {
        int d = t >> 2, c4 = t & 3;
        size_t base = (size_t)(b * 64 + d) * NPTS + n0 + c4 * 4;
        if (f32) {
            float4 pv = *(const float4*)((const float*)points + base);
            PL[d * 16 + c4 * 4 + 0] = pv.x;
            PL[d * 16 + c4 * 4 + 1] = pv.y;
            PL[d * 16 + c4 * 4 + 2] = pv.z;
            PL[d * 16 + c4 * 4 + 3] = pv.w;
        } else {
            ushort4 pv = *(const ushort4*)((const ushort_t*)points + base);
            PL[d * 16 + c4 * 4 + 0] = us2f(pv.x);
            PL[d * 16 + c4 * 4 + 1] = us2f(pv.y);
            PL[d * 16 + c4 * 4 + 2] = us2f(pv.z);
            PL[d * 16 + c4 * 4 + 3] = us2f(pv.w);
        }
    }
    __syncthreads();

    {
        int sg = lane >> 4, nl = lane & 15;
        for (int oi = 0; oi < 16; oi++) {
            int o = wid * 16 + oi;
            const float* wr = wq + o * 64 + sg * 16;
            float p = 0.f;
#pragma unroll
            for (int jj = 0; jj < 16; jj++) p = fmaf(wr[jj], PL[(sg * 16 + jj) * 16 + nl], p);
            p += __shfl_xor(p, 16, 64);
            p += __shfl_xor(p, 32, 64);
            if (lane < 16) QL[nl * 68 + o] = p;
        }
    }
    __syncthreads();

    int k = lane & 15, nsub = lane >> 4;
    int nl = wid * 4 + nsub;
    int n = n0 + nl;
    int row = (b << 12) + n;
    unsigned m = idxws[(size_t)row * 16 + k] & 4095u;

    float4 pn = xyzs[row];
    float4 pmx = xyzs[(b << 12) + (int)m];
    float rx = pn.x - pmx.x, ry = pn.y - pmx.y, rz = pn.z - pmx.z;

    float rpe[64];
#pragma unroll
    for (int d = 0; d < 64; d++) rpe[d] = bp2p[d];
#pragma unroll 2
    for (int o = 0; o < 64; o++) {
        const float* wr = wpos + o * 80;
        float hp = fmaf(wr[0], rx, fmaf(wr[1], ry, fmaf(wr[2], rz, wr[3])));
        hp = fmaxf(hp, 0.f);
#pragma unroll
        for (int d = 0; d < 64; d++) rpe[d] = fmaf(wr[4 + d], hp, rpe[d]);
    }

    float Pm[64];
#pragma unroll
    for (int d = 0; d < 64; d++)
        Pm[d] = ldin(points, ((size_t)(b * 64 + d) << 12) + (int)m, f32);

    float X[64];
    {
        const float* qrow = QL + nl * 68;
#pragma unroll 2
        for (int d = 0; d < 64; d++) {
            const float* wr = wq + (64 + d) * 64;
            float kd = 0.f;
#pragma unroll
            for (int dd = 0; dd < 64; dd++) kd = fmaf(wr[dd], Pm[dd], kd);
            X[d] = (qrow[d] - kd) + rpe[d];
        }
    }

    float sim[64];
#pragma unroll
    for (int d = 0; d < 64; d++) sim[d] = b2p[d];
#pragma unroll 2
    for (int o = 0; o < 256; o++) {
        const float* wr = wpack + (size_t)o * 144;
        float h0 = 0.f, h1 = 0.f, h2 = 0.f, h3 = 0.f;
#pragma unroll
        for (int jj = 0; jj < 16; jj++) {
            h0 = fmaf(wr[jj],      X[jj],      h0);
            h1 = fmaf(wr[16 + jj], X[16 + jj], h1);
            h2 = fmaf(wr[32 + jj], X[32 + jj], h2);
            h3 = fmaf(wr[48 + jj], X[48 + jj], h3);
        }
        float h = ((h0 + h1) + (h2 + h3)) + wr[128];
        h = fmaxf(h, 0.f);
#pragma unroll
        for (int d = 0; d < 64; d++) sim[d] = fmaf(wr[64 + d], h, sim[d]);
    }

    {
#pragma unroll
        for (int d4 = 0; d4 < 16; d4++) {
            float vvv[4];
#pragma unroll
            for (int jj = 0; jj < 4; jj++) {
                int d = 4 * d4 + jj;
                const float* wrv = wq + (128 + d) * 64;
                float vd = 0.f;
#pragma unroll
                for (int dd = 0; dd < 64; dd++) vd = fmaf(wrv[dd], Pm[dd], vd);
                vvv[jj] = vd + rpe[d];
            }
#pragma unroll
            for (int jj = 0; jj < 4; jj++) {
                int d = 4 * d4 + jj;
                float s = sim[d];
                float mx = s;
                mx = fmaxf(mx, __shfl_xor(mx, 1, 64));
                mx = fmaxf(mx, __shfl_xor(mx, 2, 64));
                mx = fmaxf(mx, __shfl_xor(mx, 4, 64));
                mx = fmaxf(mx, __shfl_xor(mx, 8, 64));
                float e = __expf(s - mx);
                float sm = e;
                sm += __shfl_xor(sm, 1, 64);
                sm += __shfl_xor(sm, 2, 64);
                sm += __shfl_xor(sm, 4, 64);
                sm += __shfl_xor(sm, 8, 64);
                float p = e * vvv[jj];
                p += __shfl_xor(p, 1, 64);
                p += __shfl_xor(p, 2, 64);
                p += __shfl_xor(p, 4, 64);
                p += __shfl_xor(p, 8, 64);
                if (k == 0) OUTS[d * 16 + nl] = p / sm;
            }
        }
    }
    __syncthreads();

    {
        int d = t >> 2, c = t & 3;
        float4 v = *(const float4*)&OUTS[d * 16 + c * 4];
        size_t ofs = (size_t)(b * 64 + d) * NPTS + n0 + c * 4;
        if (f32) {
            *(float4*)((float*)out + ofs) = v;
        } else {
            uint2 pk;
            pk.x = (unsigned)f2us(v.x) | ((unsigned)f2us(v.y) << 16);
            pk.y = (unsigned)f2us(v.z) | ((unsigned)f2us(v.w) << 16);
            *(uint2*)((ushort_t*)out + ofs) = pk;
        }
    }
}

// ---------------- host ----------------
extern "C" void kernel_launch(void* const* d_in, const int* in_sizes, int n_in,
                              void* d_out, int out_size, void* d_ws, size_t ws_size,
                              hipStream_t stream) {
    const void* xyz    = d_in[0];
    const void* points = d_in[1];
    const void* w_qkv  = d_in[2];
    const void* w_pos1 = d_in[3];
    const void* b_pos1 = d_in[4];
    const void* w_pos2 = d_in[5];
    const void* b_pos2 = d_in[6];
    const void* w_att1 = d_in[7];
    const void* b_att1 = d_in[8];
    const void* w_att2 = d_in[9];
    const void* b_att2 = d_in[10];
    float* ws = (float*)d_ws;

    int use_kv = ws_size >= FULL_FLOATS * sizeof(float) ? 1 : 0;

    hipLaunchKernelGGL(detect_kernel, dim3(1), dim3(256), 0, stream,
                       xyz, (unsigned*)ws + OFF_FLAG);
    hipLaunchKernelGGL(prep_kernel, dim3(68), dim3(256), 0, stream,
                       xyz, w_qkv, w_pos1, b_pos1, w_pos2, b_pos2,
                       w_att1, b_att1, w_att2, b_att2, ws, use_kv);
    if (use_kv)
        hipLaunchKernelGGL(kv_kernel, dim3(256), dim3(256), 0, stream, points, ws);
    hipLaunchKernelGGL(knn_kernel, dim3(4096), dim3(256), 0, stream, ws);
    if (use_kv)
        hipLaunchKernelGGL(pt_mfma, dim3(2048), dim3(256), 0, stream, (const float*)ws, points, d_out);
    else
        hipLaunchKernelGGL(pt_main_compact, dim3(1024), dim3(256), 0, stream, (const float*)ws, points, d_out);
}